// Round 1
// baseline (326.250 us; speedup 1.0000x reference)
//
#include <hip/hip_runtime.h>
#include <hip/hip_bf16.h>
#include <math.h>

// Problem constants
#define B 64
#define T 1000
#define RNN_DIM 1024
#define EMB_DIM 512
#define ATT_DIM 128
#define LOC_DIM 32
#define KSIZE 31
#define PAD 15          // SAME padding for K=31
#define ET 64           // t-positions per energy block (16 tiles, last partial)
#define ESL 32          // e-floats per context block slice (16 slices)

// ---------------------------------------------------------------------------
// Kernel 1: pq[b][a] = dot(hidden[b, :1024], Wq[a, :1024])
// One wave per output. 8192 outputs -> 2048 blocks x 256 threads. (~5 us, L2-fed)
// ---------------------------------------------------------------------------
__global__ __launch_bounds__(256) void pq_kernel(
    const float* __restrict__ hidden,   // (B, 1024)
    const float* __restrict__ Wq,       // (128, 1024)
    float* __restrict__ pq)             // (B, 128)
{
    int gwave = (blockIdx.x * blockDim.x + threadIdx.x) >> 6;
    int lane  = threadIdx.x & 63;
    int b = gwave >> 7;     // / 128
    int a = gwave & 127;

    const float4* h4 = (const float4*)(hidden + (size_t)b * RNN_DIM);
    const float4* w4 = (const float4*)(Wq + (size_t)a * RNN_DIM);

    float acc = 0.f;
#pragma unroll
    for (int j = 0; j < 4; ++j) {
        float4 h = h4[j * 64 + lane];
        float4 w = w4[j * 64 + lane];
        acc += h.x * w.x + h.y * w.y + h.z * w.z + h.w * w.w;
    }
#pragma unroll
    for (int off = 32; off > 0; off >>= 1)
        acc += __shfl_down(acc, off, 64);
    if (lane == 0) pq[gwave] = acc;
}

// ---------------------------------------------------------------------------
// Kernel 2: fused location conv + W_loc projection + tanh + v-dot -> energy.
// R5 rewrite of phase 2: thread = (TL=tid>>4 -> 4 t's, AL=tid&15, a=AL+16*aa).
//  - wl rows live in registers per aa, reused across 4 t's:
//    ds_read_b128 per thread 264 -> 96 (was the LDS-pipe bottleneck, ~1 MB of
//    LDS reads per block for a 16 KB matrix).
//  - pm is loaded straight from global into registers at kernel entry (32
//    scalar loads/thread, 64B-coalesced per 16-lane group); issue is hidden
//    under staging+conv. Removes the 33 KB pm LDS stage + one barrier.
//  - LDS 37.4 KB; VGPR ~230 capped by __launch_bounds__(256,2).
// ---------------------------------------------------------------------------
__global__ __launch_bounds__(256, 2) void energy_kernel(
    const float* __restrict__ aw,       // (B, 2, T)
    const float* __restrict__ cw,       // (32, 2, 31)
    const float* __restrict__ wl,       // (128, 32)
    const float* __restrict__ pq,       // (B, 128)
    const float* __restrict__ pm,       // (B, T, 128)
    const float* __restrict__ v,        // (128)
    float* __restrict__ energy)         // (B, T)
{
    __shared__ float aw_lds[2][ET + 2 * PAD];     // [2][94]
    __shared__ float cw_lds[LOC_DIM][2][KSIZE];   // bank: 2-way, free
    __shared__ float wl_lds[ATT_DIM][36];         // stride 36: a=AL+16aa -> 2-way, free
    __shared__ float pq_lds[ATT_DIM];
    __shared__ float v_lds[ATT_DIM];
    __shared__ float loc_lds[ET][36];             // stride 36: b128 reads 16B-aligned

    const int b   = blockIdx.x;
    const int t0  = blockIdx.y * ET;
    const int tid = threadIdx.x;

    const int TL = tid >> 4;      // 0..15: t-quad
    const int AL = tid & 15;      // 0..15: a-lane
    const int tb = TL * 4;

    // ---- issue pm loads into registers immediately (latency hides under conv)
    float pmr[4][8];
#pragma unroll
    for (int jj = 0; jj < 4; ++jj) {
        const int t = t0 + tb + jj;
        const bool ok = (t < T);
        const float* prow = pm + ((size_t)b * T + (ok ? t : T - 1)) * ATT_DIM;
#pragma unroll
        for (int aa = 0; aa < 8; ++aa)
            pmr[jj][aa] = ok ? prow[AL + 16 * aa] : 0.f;
    }

    // ---- stage small weights ----
    for (int i = tid; i < LOC_DIM * 2 * KSIZE; i += 256)
        ((float*)cw_lds)[i] = cw[i];
    for (int i = tid; i < ATT_DIM * LOC_DIM; i += 256)
        wl_lds[i >> 5][i & 31] = wl[i];
    if (tid < ATT_DIM) {
        pq_lds[tid] = pq[b * ATT_DIM + tid];
        v_lds[tid]  = v[tid];
    }
    for (int i = tid; i < 2 * (ET + 2 * PAD); i += 256) {
        int ch = i / (ET + 2 * PAD);
        int p  = i % (ET + 2 * PAD);
        int t  = t0 + p - PAD;
        aw_lds[ch][p] = (t >= 0 && t < T) ? aw[(size_t)b * 2 * T + ch * T + t] : 0.f;
    }
    __syncthreads();

    // ---- Phase 1: conv. thread = (c = tid&31, tg = tid>>5), 8 t's each ----
    {
        const int c  = tid & 31;
        const int tg = tid >> 5;
        float acc[8];
#pragma unroll
        for (int j = 0; j < 8; ++j) acc[j] = 0.f;
#pragma unroll
        for (int ch = 0; ch < 2; ++ch) {
            float awr[KSIZE + 7];   // 38-float sliding window in registers
#pragma unroll
            for (int j = 0; j < KSIZE + 7; ++j) awr[j] = aw_lds[ch][tg * 8 + j];
#pragma unroll
            for (int k = 0; k < KSIZE; ++k) {
                float cv = cw_lds[c][ch][k];   // 2-way broadcast, free
#pragma unroll
                for (int j = 0; j < 8; ++j) acc[j] += cv * awr[k + j];
            }
        }
#pragma unroll
        for (int j = 0; j < 8; ++j) loc_lds[tg * 8 + j][c] = acc[j];
    }
    __syncthreads();

    // ---- Phase 2: 4 t's per thread, wl rows register-resident per aa ----
    {
        float lr[4][32];   // 4 loc rows in registers (128 VGPR)
#pragma unroll
        for (int jj = 0; jj < 4; ++jj)
#pragma unroll
            for (int q = 0; q < 8; ++q)
                *((float4*)&lr[jj][4 * q]) = *((const float4*)&loc_lds[tb + jj][4 * q]);

        float acc[4] = {0.f, 0.f, 0.f, 0.f};
#pragma unroll
        for (int aa = 0; aa < 8; ++aa) {
            const int a = AL + 16 * aa;     // 16 lanes -> 16 distinct banks
            const float pqa = pq_lds[a];
            const float va  = v_lds[a];
            float4 w[8];
#pragma unroll
            for (int q = 0; q < 8; ++q)
                w[q] = *((const float4*)&wl_lds[a][4 * q]);
#pragma unroll
            for (int jj = 0; jj < 4; ++jj) {
                float e = pqa + pmr[jj][aa];
#pragma unroll
                for (int q = 0; q < 8; ++q) {
                    e += w[q].x * lr[jj][4*q]   + w[q].y * lr[jj][4*q+1]
                       + w[q].z * lr[jj][4*q+2] + w[q].w * lr[jj][4*q+3];
                }
                // fast tanh: 1 - 2/(1+exp(2e)); ~5 VALU ops, abs err ~1e-6
                float ex = __expf(2.f * e);
                float th = 1.f - 2.f * __builtin_amdgcn_rcpf(1.f + ex);
                acc[jj] += va * th;
            }
        }
        // reduce over the 16 a-lanes (xor 1,2,4,8 stays within the 16-group)
#pragma unroll
        for (int jj = 0; jj < 4; ++jj) {
            float s = acc[jj];
            s += __shfl_xor(s, 1, 64);
            s += __shfl_xor(s, 2, 64);
            s += __shfl_xor(s, 4, 64);
            s += __shfl_xor(s, 8, 64);
            if (AL == 0) {
                int t = t0 + tb + jj;
                if (t < T) energy[b * T + t] = s;
            }
        }
    }
}

// ---------------------------------------------------------------------------
// Kernel 3: softmax over T per batch row; writes weights to d_out tail.
// (ctx zeroing removed: context kernel now writes every output exactly once.)
// ---------------------------------------------------------------------------
__global__ __launch_bounds__(256) void softmax_kernel(
    const float* __restrict__ energy,        // (B, T) in ws
    const unsigned char* __restrict__ mask,  // (B, T) bool
    float* __restrict__ out)                 // [B*512 ctx][B*1000 weights]
{
    int b   = blockIdx.x;
    int tid = threadIdx.x;

    __shared__ float red[4];
    float e[4];
    float mx = -INFINITY;
#pragma unroll
    for (int j = 0; j < 4; ++j) {
        int t = tid + j * 256;
        if (t < T) {
            float val = energy[b * T + t];
            if (mask[b * T + t]) val = -INFINITY;
            e[j] = val;
            mx = fmaxf(mx, val);
        } else e[j] = -INFINITY;
    }
#pragma unroll
    for (int off = 32; off > 0; off >>= 1)
        mx = fmaxf(mx, __shfl_down(mx, off, 64));
    if ((tid & 63) == 0) red[tid >> 6] = mx;
    __syncthreads();
    mx = fmaxf(fmaxf(red[0], red[1]), fmaxf(red[2], red[3]));
    __syncthreads();

    float sum = 0.f;
    float ex[4];
#pragma unroll
    for (int j = 0; j < 4; ++j) {
        ex[j] = (e[j] == -INFINITY) ? 0.f : expf(e[j] - mx);
        sum += ex[j];
    }
#pragma unroll
    for (int off = 32; off > 0; off >>= 1)
        sum += __shfl_down(sum, off, 64);
    if ((tid & 63) == 0) red[tid >> 6] = sum;
    __syncthreads();
    sum = red[0] + red[1] + red[2] + red[3];
    float inv = 1.f / sum;
#pragma unroll
    for (int j = 0; j < 4; ++j) {
        int t = tid + j * 256;
        if (t < T) out[B * EMB_DIM + b * T + t] = ex[j] * inv;
    }
}

// ---------------------------------------------------------------------------
// Kernel 4 (R5 rewrite): context[b][e] = sum_t w[b][t] * memory[b][t][e]
// Grid (64 b, 16 e-slices of 32 floats) = 1024 blocks (4/CU, one occupancy
// round). Thread = (rg = tid>>3 row-group, col = tid&7 float4-in-slice):
//  - every wave-load = 8 rows x 128 B aligned contiguous segments (full
//    cacheline utilization; old layout was stride-32B interleaved -> 2x
//    transaction rate).
//  - 8 loads batched into registers per step (forced ILP, 16 waves/CU x 8
//    outstanding 1 KB wave-loads = 131 KB in flight/CU >> 9 KB Little's-law
//    requirement at 900cy HBM latency).
//  - NO atomics: per-thread partials -> shfl butterfly over rg-in-wave ->
//    128 B LDS cross-wave reduce -> one plain 128 B store per block.
// ---------------------------------------------------------------------------
__global__ __launch_bounds__(256) void context_kernel(
    const float* __restrict__ memory,   // (B, T, 512)
    const float* __restrict__ w,        // weights at d_out + B*512
    float* __restrict__ ctx)            // d_out context region
{
    __shared__ float w_lds[1024];       // T padded to 1024, pad weight = 0
    __shared__ float red[4][ESL];

    const int b   = blockIdx.x;
    const int e0  = blockIdx.y * ESL;
    const int tid = threadIdx.x;
    const int col = tid & 7;            // float4 index within 32-float slice
    const int rg  = tid >> 3;           // 0..31 row-group

    for (int i = tid; i < 1024; i += 256)
        w_lds[i] = (i < T) ? w[b * T + i] : 0.f;
    __syncthreads();

    const float4* mem4 = (const float4*)(memory + (size_t)b * T * EMB_DIM + e0);

    float4 acc = {0.f, 0.f, 0.f, 0.f};
    float4 mbuf[8];
#pragma unroll 1
    for (int blk = 0; blk < 4; ++blk) {
        const int rbase = blk * 256 + rg;
        // phase A: 8 independent coalesced loads (row r = rbase + 32u)
#pragma unroll
        for (int u = 0; u < 8; ++u) {
            int r  = rbase + 32 * u;
            int rc = (r < T) ? r : (T - 1);            // clamp: stay in bounds
            mbuf[u] = mem4[(size_t)rc * 128 + col];
        }
        // phase B: accumulate (pad rows killed by w=0)
#pragma unroll
        for (int u = 0; u < 8; ++u) {
            float wt = w_lds[rbase + 32 * u];          // 8 addrs/wave, conflict-free
            acc.x += wt * mbuf[u].x; acc.y += wt * mbuf[u].y;
            acc.z += wt * mbuf[u].z; acc.w += wt * mbuf[u].w;
        }
    }

    // in-wave butterfly over the 8 rg-groups (lanes l^8, l^16, l^32; col fixed)
    acc.x += __shfl_xor(acc.x, 8, 64);  acc.x += __shfl_xor(acc.x, 16, 64);  acc.x += __shfl_xor(acc.x, 32, 64);
    acc.y += __shfl_xor(acc.y, 8, 64);  acc.y += __shfl_xor(acc.y, 16, 64);  acc.y += __shfl_xor(acc.y, 32, 64);
    acc.z += __shfl_xor(acc.z, 8, 64);  acc.z += __shfl_xor(acc.z, 16, 64);  acc.z += __shfl_xor(acc.z, 32, 64);
    acc.w += __shfl_xor(acc.w, 8, 64);  acc.w += __shfl_xor(acc.w, 16, 64);  acc.w += __shfl_xor(acc.w, 32, 64);

    if ((tid & 63) < 8)
        *((float4*)&red[tid >> 6][4 * col]) = acc;
    __syncthreads();
    if (tid < ESL) {
        float s = red[0][tid] + red[1][tid] + red[2][tid] + red[3][tid];
        ctx[b * EMB_DIM + e0 + tid] = s;
    }
}

// ---------------------------------------------------------------------------
extern "C" void kernel_launch(void* const* d_in, const int* in_sizes, int n_in,
                              void* d_out, int out_size, void* d_ws, size_t ws_size,
                              hipStream_t stream) {
    const float* hidden = (const float*)d_in[0];            // (64, 1024)
    const float* memory = (const float*)d_in[1];            // (64, 1000, 512)
    const float* pm     = (const float*)d_in[2];            // (64, 1000, 128)
    const float* aw     = (const float*)d_in[3];            // (64, 2, 1000)
    const unsigned char* mask = (const unsigned char*)d_in[4]; // (64, 1000) bool
    const float* Wq     = (const float*)d_in[5];            // (128, 1024)
    const float* cw     = (const float*)d_in[6];            // (32, 2, 31)
    const float* wl     = (const float*)d_in[7];            // (128, 32)
    const float* v      = (const float*)d_in[8];            // (1, 128)

    float* out = (float*)d_out;            // [B*512 context][B*1000 weights]

    // workspace layout
    float* pq_ws     = (float*)d_ws;                   // B*128
    float* energy_ws = pq_ws + B * ATT_DIM;            // B*T

    // 1) query projection: 8192 waves
    pq_kernel<<<dim3((B * ATT_DIM) / 4), dim3(256), 0, stream>>>(hidden, Wq, pq_ws);

    // 2) fused conv/proj/tanh/v-dot -> energy  (16 tiles of 64 t)
    energy_kernel<<<dim3(B, (T + ET - 1) / ET), dim3(256), 0, stream>>>(
        aw, cw, wl, pq_ws, pm, v, energy_ws);

    // 3) softmax (writes weights to out tail)
    softmax_kernel<<<dim3(B), dim3(256), 0, stream>>>(energy_ws, mask, out);

    // 4) context accumulation: (64 b, 16 e-slices), no atomics
    context_kernel<<<dim3(B, EMB_DIM / ESL), dim3(256), 0, stream>>>(
        memory, out + B * EMB_DIM, out);
}

// Round 2
// 273.081 us; speedup vs baseline: 1.1947x; 1.1947x over previous
//
#include <hip/hip_runtime.h>
#include <hip/hip_bf16.h>
#include <math.h>

// Problem constants
#define B 64
#define T 1000
#define RNN_DIM 1024
#define EMB_DIM 512
#define ATT_DIM 128
#define LOC_DIM 32
#define KSIZE 31
#define PAD 15          // SAME padding for K=31
#define ET 64           // t-positions per energy block (16 tiles, last partial)
#define ESL 32          // e-floats per context block slice (16 slices)

// ---------------------------------------------------------------------------
// Kernel 1: pq[b][a] = dot(hidden[b, :1024], Wq[a, :1024])
// One wave per output. 8192 outputs -> 2048 blocks x 256 threads. (~5 us, L2-fed)
// ---------------------------------------------------------------------------
__global__ __launch_bounds__(256) void pq_kernel(
    const float* __restrict__ hidden,   // (B, 1024)
    const float* __restrict__ Wq,       // (128, 1024)
    float* __restrict__ pq)             // (B, 128)
{
    int gwave = (blockIdx.x * blockDim.x + threadIdx.x) >> 6;
    int lane  = threadIdx.x & 63;
    int b = gwave >> 7;     // / 128
    int a = gwave & 127;

    const float4* h4 = (const float4*)(hidden + (size_t)b * RNN_DIM);
    const float4* w4 = (const float4*)(Wq + (size_t)a * RNN_DIM);

    float acc = 0.f;
#pragma unroll
    for (int j = 0; j < 4; ++j) {
        float4 h = h4[j * 64 + lane];
        float4 w = w4[j * 64 + lane];
        acc += h.x * w.x + h.y * w.y + h.z * w.z + h.w * w.w;
    }
#pragma unroll
    for (int off = 32; off > 0; off >>= 1)
        acc += __shfl_down(acc, off, 64);
    if (lane == 0) pq[gwave] = acc;
}

// ---------------------------------------------------------------------------
// Kernel 2: fused location conv + W_loc projection + tanh + v-dot -> energy.
// R6: R5's Nt=4 x Na=8 tiling (96 b128 LDS reads/thread, vs 264 in R0-R4)
// but register-budgeted. R5 spilled catastrophically (176 MB scratch writes
// per dispatch, VALUBusy 14%): lr[4][32]=128 + pmr 32 + w 32 ~ 190 live floats
// vs the 128-VGPR allocation. Fix: split K=32 into 4 chunks of 8 so the loc
// tile is lrh[4][8]=32 regs; pm lives IN the accumulator acc_e[4][8] (loaded
// from global before staging so HBM latency hides under conv); pq added in
// the epilogue. Peak ~100 VGPR -> no spill, 4 blocks/CU (LDS-capped at 37 KB).
// ---------------------------------------------------------------------------
__global__ __launch_bounds__(256) void energy_kernel(
    const float* __restrict__ aw,       // (B, 2, T)
    const float* __restrict__ cw,       // (32, 2, 31)
    const float* __restrict__ wl,       // (128, 32)
    const float* __restrict__ pq,       // (B, 128)
    const float* __restrict__ pm,       // (B, T, 128)
    const float* __restrict__ v,        // (128)
    float* __restrict__ energy)         // (B, T)
{
    __shared__ float aw_lds[2][ET + 2 * PAD];     // [2][94]
    __shared__ float cw_lds[LOC_DIM][2][KSIZE];   // bank: 2-way, free
    __shared__ float wl_lds[ATT_DIM][36];         // stride 36: a=AL+16aa -> 2-way, free
    __shared__ float pq_lds[ATT_DIM];
    __shared__ float v_lds[ATT_DIM];
    __shared__ float loc_lds[ET][36];             // stride 36: b128 2-way, free

    const int b   = blockIdx.x;
    const int t0  = blockIdx.y * ET;
    const int tid = threadIdx.x;

    const int TL = tid >> 4;      // 0..15: t-quad
    const int AL = tid & 15;      // 0..15: a-lane
    const int tb = TL * 4;

    // ---- pm straight into the accumulator; issue before staging so the
    //      ~900cy HBM latency hides under the weight staging + conv phase.
    //      Coalescing: 16 AL lanes read 16 consecutive floats (64B segment).
    float acc_e[4][8];
#pragma unroll
    for (int jj = 0; jj < 4; ++jj) {
        const int t = t0 + tb + jj;
        const bool ok = (t < T);
        const float* prow = pm + ((size_t)b * T + (ok ? t : 0)) * ATT_DIM + AL;
#pragma unroll
        for (int aa = 0; aa < 8; ++aa)
            acc_e[jj][aa] = ok ? prow[16 * aa] : 0.f;
    }

    // ---- stage small weights ----
    for (int i = tid; i < LOC_DIM * 2 * KSIZE; i += 256)
        ((float*)cw_lds)[i] = cw[i];
    for (int i = tid; i < ATT_DIM * LOC_DIM; i += 256)
        wl_lds[i >> 5][i & 31] = wl[i];
    if (tid < ATT_DIM) {
        pq_lds[tid] = pq[b * ATT_DIM + tid];
        v_lds[tid]  = v[tid];
    }
    for (int i = tid; i < 2 * (ET + 2 * PAD); i += 256) {
        int ch = i / (ET + 2 * PAD);
        int p  = i % (ET + 2 * PAD);
        int t  = t0 + p - PAD;
        aw_lds[ch][p] = (t >= 0 && t < T) ? aw[(size_t)b * 2 * T + ch * T + t] : 0.f;
    }
    __syncthreads();

    // ---- Phase 1: conv. thread = (c = tid&31, tg = tid>>5), 8 t's each ----
    {
        const int c  = tid & 31;
        const int tg = tid >> 5;
        float acc[8];
#pragma unroll
        for (int j = 0; j < 8; ++j) acc[j] = 0.f;
#pragma unroll
        for (int ch = 0; ch < 2; ++ch) {
            float awr[KSIZE + 7];   // 38-float sliding window in registers
#pragma unroll
            for (int j = 0; j < KSIZE + 7; ++j) awr[j] = aw_lds[ch][tg * 8 + j];
#pragma unroll
            for (int k = 0; k < KSIZE; ++k) {
                float cv = cw_lds[c][ch][k];   // 2-way broadcast, free
#pragma unroll
                for (int j = 0; j < 8; ++j) acc[j] += cv * awr[k + j];
            }
        }
#pragma unroll
        for (int j = 0; j < 8; ++j) loc_lds[tg * 8 + j][c] = acc[j];
    }
    __syncthreads();

    // ---- Phase 2: 4 t's x 8 a's per thread, K split into 4 chunks of 8.
    //      LDS reads: loc 4t x 4h x 2 = 32 b128, wl 8a x 4h x 2 = 64 b128.
    //      Banks: 16 AL lanes broadcast loc rows (4 distinct rows, 2-way);
    //      wl rows a=AL+16aa at stride 36 -> (4a)%32, 2-way. All free.
#pragma unroll
    for (int h = 0; h < 4; ++h) {
        float lrh[4][8];
#pragma unroll
        for (int jj = 0; jj < 4; ++jj) {
            *((float4*)&lrh[jj][0]) = *((const float4*)&loc_lds[tb + jj][8 * h]);
            *((float4*)&lrh[jj][4]) = *((const float4*)&loc_lds[tb + jj][8 * h + 4]);
        }
#pragma unroll
        for (int aa = 0; aa < 8; ++aa) {
            const int a = AL + 16 * aa;
            float4 w0 = *((const float4*)&wl_lds[a][8 * h]);
            float4 w1 = *((const float4*)&wl_lds[a][8 * h + 4]);
#pragma unroll
            for (int jj = 0; jj < 4; ++jj) {
                acc_e[jj][aa] +=
                      w0.x * lrh[jj][0] + w0.y * lrh[jj][1]
                    + w0.z * lrh[jj][2] + w0.w * lrh[jj][3]
                    + w1.x * lrh[jj][4] + w1.y * lrh[jj][5]
                    + w1.z * lrh[jj][6] + w1.w * lrh[jj][7];
            }
        }
    }

    // ---- epilogue: e = acc_e + pq; tanh; v-dot; reduce over 16 AL lanes ----
    float acc[4] = {0.f, 0.f, 0.f, 0.f};
#pragma unroll
    for (int aa = 0; aa < 8; ++aa) {
        const int a = AL + 16 * aa;
        const float pqa = pq_lds[a];
        const float va  = v_lds[a];
#pragma unroll
        for (int jj = 0; jj < 4; ++jj) {
            float e = acc_e[jj][aa] + pqa;
            // fast tanh: 1 - 2/(1+exp(2e)); ~5 VALU ops, abs err ~1e-6
            float ex = __expf(2.f * e);
            float th = 1.f - 2.f * __builtin_amdgcn_rcpf(1.f + ex);
            acc[jj] += va * th;
        }
    }
#pragma unroll
    for (int jj = 0; jj < 4; ++jj) {
        float s = acc[jj];
        s += __shfl_xor(s, 1, 64);
        s += __shfl_xor(s, 2, 64);
        s += __shfl_xor(s, 4, 64);
        s += __shfl_xor(s, 8, 64);
        if (AL == 0) {
            int t = t0 + tb + jj;
            if (t < T) energy[b * T + t] = s;
        }
    }
}

// ---------------------------------------------------------------------------
// Kernel 3: softmax over T per batch row; writes weights to d_out tail.
// ---------------------------------------------------------------------------
__global__ __launch_bounds__(256) void softmax_kernel(
    const float* __restrict__ energy,        // (B, T) in ws
    const unsigned char* __restrict__ mask,  // (B, T) bool
    float* __restrict__ out)                 // [B*512 ctx][B*1000 weights]
{
    int b   = blockIdx.x;
    int tid = threadIdx.x;

    __shared__ float red[4];
    float e[4];
    float mx = -INFINITY;
#pragma unroll
    for (int j = 0; j < 4; ++j) {
        int t = tid + j * 256;
        if (t < T) {
            float val = energy[b * T + t];
            if (mask[b * T + t]) val = -INFINITY;
            e[j] = val;
            mx = fmaxf(mx, val);
        } else e[j] = -INFINITY;
    }
#pragma unroll
    for (int off = 32; off > 0; off >>= 1)
        mx = fmaxf(mx, __shfl_down(mx, off, 64));
    if ((tid & 63) == 0) red[tid >> 6] = mx;
    __syncthreads();
    mx = fmaxf(fmaxf(red[0], red[1]), fmaxf(red[2], red[3]));
    __syncthreads();

    float sum = 0.f;
    float ex[4];
#pragma unroll
    for (int j = 0; j < 4; ++j) {
        ex[j] = (e[j] == -INFINITY) ? 0.f : expf(e[j] - mx);
        sum += ex[j];
    }
#pragma unroll
    for (int off = 32; off > 0; off >>= 1)
        sum += __shfl_down(sum, off, 64);
    if ((tid & 63) == 0) red[tid >> 6] = sum;
    __syncthreads();
    sum = red[0] + red[1] + red[2] + red[3];
    float inv = 1.f / sum;
#pragma unroll
    for (int j = 0; j < 4; ++j) {
        int t = tid + j * 256;
        if (t < T) out[B * EMB_DIM + b * T + t] = ex[j] * inv;
    }
}

// ---------------------------------------------------------------------------
// Kernel 4: context[b][e] = sum_t w[b][t] * memory[b][t][e]
// Grid (64 b, 16 e-slices of 32 floats) = 1024 blocks. Thread = (rg = tid>>3
// row-group, col = tid&7 float4-in-slice): every wave-load = 8 rows x 128 B
// aligned contiguous segments; 8 loads batched per step (forced ILP); no
// atomics: shfl butterfly + 128 B LDS reduce + one plain store per block.
// ---------------------------------------------------------------------------
__global__ __launch_bounds__(256) void context_kernel(
    const float* __restrict__ memory,   // (B, T, 512)
    const float* __restrict__ w,        // weights at d_out + B*512
    float* __restrict__ ctx)            // d_out context region
{
    __shared__ float w_lds[1024];       // T padded to 1024, pad weight = 0
    __shared__ float red[4][ESL];

    const int b   = blockIdx.x;
    const int e0  = blockIdx.y * ESL;
    const int tid = threadIdx.x;
    const int col = tid & 7;            // float4 index within 32-float slice
    const int rg  = tid >> 3;           // 0..31 row-group

    for (int i = tid; i < 1024; i += 256)
        w_lds[i] = (i < T) ? w[b * T + i] : 0.f;
    __syncthreads();

    const float4* mem4 = (const float4*)(memory + (size_t)b * T * EMB_DIM + e0);

    float4 acc = {0.f, 0.f, 0.f, 0.f};
    float4 mbuf[8];
#pragma unroll 1
    for (int blk = 0; blk < 4; ++blk) {
        const int rbase = blk * 256 + rg;
        // phase A: 8 independent coalesced loads (row r = rbase + 32u)
#pragma unroll
        for (int u = 0; u < 8; ++u) {
            int r  = rbase + 32 * u;
            int rc = (r < T) ? r : (T - 1);            // clamp: stay in bounds
            mbuf[u] = mem4[(size_t)rc * 128 + col];
        }
        // phase B: accumulate (pad rows killed by w=0)
#pragma unroll
        for (int u = 0; u < 8; ++u) {
            float wt = w_lds[rbase + 32 * u];          // 8 addrs/wave, conflict-free
            acc.x += wt * mbuf[u].x; acc.y += wt * mbuf[u].y;
            acc.z += wt * mbuf[u].z; acc.w += wt * mbuf[u].w;
        }
    }

    // in-wave butterfly over the 8 rg-groups (lanes l^8, l^16, l^32; col fixed)
    acc.x += __shfl_xor(acc.x, 8, 64);  acc.x += __shfl_xor(acc.x, 16, 64);  acc.x += __shfl_xor(acc.x, 32, 64);
    acc.y += __shfl_xor(acc.y, 8, 64);  acc.y += __shfl_xor(acc.y, 16, 64);  acc.y += __shfl_xor(acc.y, 32, 64);
    acc.z += __shfl_xor(acc.z, 8, 64);  acc.z += __shfl_xor(acc.z, 16, 64);  acc.z += __shfl_xor(acc.z, 32, 64);
    acc.w += __shfl_xor(acc.w, 8, 64);  acc.w += __shfl_xor(acc.w, 16, 64);  acc.w += __shfl_xor(acc.w, 32, 64);

    if ((tid & 63) < 8)
        *((float4*)&red[tid >> 6][4 * col]) = acc;
    __syncthreads();
    if (tid < ESL) {
        float s = red[0][tid] + red[1][tid] + red[2][tid] + red[3][tid];
        ctx[b * EMB_DIM + e0 + tid] = s;
    }
}

// ---------------------------------------------------------------------------
extern "C" void kernel_launch(void* const* d_in, const int* in_sizes, int n_in,
                              void* d_out, int out_size, void* d_ws, size_t ws_size,
                              hipStream_t stream) {
    const float* hidden = (const float*)d_in[0];            // (64, 1024)
    const float* memory = (const float*)d_in[1];            // (64, 1000, 512)
    const float* pm     = (const float*)d_in[2];            // (64, 1000, 128)
    const float* aw     = (const float*)d_in[3];            // (64, 2, 1000)
    const unsigned char* mask = (const unsigned char*)d_in[4]; // (64, 1000) bool
    const float* Wq     = (const float*)d_in[5];            // (128, 1024)
    const float* cw     = (const float*)d_in[6];            // (32, 2, 31)
    const float* wl     = (const float*)d_in[7];            // (128, 32)
    const float* v      = (const float*)d_in[8];            // (1, 128)

    float* out = (float*)d_out;            // [B*512 context][B*1000 weights]

    // workspace layout
    float* pq_ws     = (float*)d_ws;                   // B*128
    float* energy_ws = pq_ws + B * ATT_DIM;            // B*T

    // 1) query projection: 8192 waves
    pq_kernel<<<dim3((B * ATT_DIM) / 4), dim3(256), 0, stream>>>(hidden, Wq, pq_ws);

    // 2) fused conv/proj/tanh/v-dot -> energy  (16 tiles of 64 t)
    energy_kernel<<<dim3(B, (T + ET - 1) / ET), dim3(256), 0, stream>>>(
        aw, cw, wl, pq_ws, pm, v, energy_ws);

    // 3) softmax (writes weights to out tail)
    softmax_kernel<<<dim3(B), dim3(256), 0, stream>>>(energy_ws, mask, out);

    // 4) context accumulation: (64 b, 16 e-slices), no atomics
    context_kernel<<<dim3(B, EMB_DIM / ESL), dim3(256), 0, stream>>>(
        memory, out + B * EMB_DIM, out);
}

// Round 4
// 267.801 us; speedup vs baseline: 1.2183x; 1.0197x over previous
//
#include <hip/hip_runtime.h>
#include <hip/hip_bf16.h>
#include <math.h>

// Problem constants
#define B 64
#define T 1000
#define RNN_DIM 1024
#define EMB_DIM 512
#define ATT_DIM 128
#define LOC_DIM 32
#define KSIZE 31
#define PAD 15          // SAME padding for K=31
#define ET 64           // t-positions per energy block (16 tiles, last partial)
#define ESL 32          // e-floats per context block slice (16 slices)

// ---------------------------------------------------------------------------
// Kernel 1: pq[b][a] = dot(hidden[b, :1024], Wq[a, :1024])
// One wave per output. 8192 outputs -> 2048 blocks x 256 threads. (~5 us, L2-fed)
// ---------------------------------------------------------------------------
__global__ __launch_bounds__(256) void pq_kernel(
    const float* __restrict__ hidden,   // (B, 1024)
    const float* __restrict__ Wq,       // (128, 1024)
    float* __restrict__ pq)             // (B, 128)
{
    int gwave = (blockIdx.x * blockDim.x + threadIdx.x) >> 6;
    int lane  = threadIdx.x & 63;
    int b = gwave >> 7;     // / 128
    int a = gwave & 127;

    const float4* h4 = (const float4*)(hidden + (size_t)b * RNN_DIM);
    const float4* w4 = (const float4*)(Wq + (size_t)a * RNN_DIM);

    float acc = 0.f;
#pragma unroll
    for (int j = 0; j < 4; ++j) {
        float4 h = h4[j * 64 + lane];
        float4 w = w4[j * 64 + lane];
        acc += h.x * w.x + h.y * w.y + h.z * w.z + h.w * w.w;
    }
#pragma unroll
    for (int off = 32; off > 0; off >>= 1)
        acc += __shfl_down(acc, off, 64);
    if (lane == 0) pq[gwave] = acc;
}

// ---------------------------------------------------------------------------
// Kernel 2: fused location conv + W_loc projection + tanh + v-dot -> energy.
// R6 structure (register-budgeted Nt=4 x Na=8 tiling, K split into 4 chunks
// of 8; pm lives in the accumulator, loaded from global before staging).
// No spills (R2 profile: off top-5). Unchanged this round.
// ---------------------------------------------------------------------------
__global__ __launch_bounds__(256) void energy_kernel(
    const float* __restrict__ aw,       // (B, 2, T)
    const float* __restrict__ cw,       // (32, 2, 31)
    const float* __restrict__ wl,       // (128, 32)
    const float* __restrict__ pq,       // (B, 128)
    const float* __restrict__ pm,       // (B, T, 128)
    const float* __restrict__ v,        // (128)
    float* __restrict__ energy)         // (B, T)
{
    __shared__ float aw_lds[2][ET + 2 * PAD];     // [2][94]
    __shared__ float cw_lds[LOC_DIM][2][KSIZE];   // bank: 2-way, free
    __shared__ float wl_lds[ATT_DIM][36];         // stride 36: a=AL+16aa -> 2-way, free
    __shared__ float pq_lds[ATT_DIM];
    __shared__ float v_lds[ATT_DIM];
    __shared__ float loc_lds[ET][36];             // stride 36: b128 2-way, free

    const int b   = blockIdx.x;
    const int t0  = blockIdx.y * ET;
    const int tid = threadIdx.x;

    const int TL = tid >> 4;      // 0..15: t-quad
    const int AL = tid & 15;      // 0..15: a-lane
    const int tb = TL * 4;

    // ---- pm straight into the accumulator; issue before staging so the
    //      ~900cy HBM latency hides under the weight staging + conv phase.
    float acc_e[4][8];
#pragma unroll
    for (int jj = 0; jj < 4; ++jj) {
        const int t = t0 + tb + jj;
        const bool ok = (t < T);
        const float* prow = pm + ((size_t)b * T + (ok ? t : 0)) * ATT_DIM + AL;
#pragma unroll
        for (int aa = 0; aa < 8; ++aa)
            acc_e[jj][aa] = ok ? prow[16 * aa] : 0.f;
    }

    // ---- stage small weights ----
    for (int i = tid; i < LOC_DIM * 2 * KSIZE; i += 256)
        ((float*)cw_lds)[i] = cw[i];
    for (int i = tid; i < ATT_DIM * LOC_DIM; i += 256)
        wl_lds[i >> 5][i & 31] = wl[i];
    if (tid < ATT_DIM) {
        pq_lds[tid] = pq[b * ATT_DIM + tid];
        v_lds[tid]  = v[tid];
    }
    for (int i = tid; i < 2 * (ET + 2 * PAD); i += 256) {
        int ch = i / (ET + 2 * PAD);
        int p  = i % (ET + 2 * PAD);
        int t  = t0 + p - PAD;
        aw_lds[ch][p] = (t >= 0 && t < T) ? aw[(size_t)b * 2 * T + ch * T + t] : 0.f;
    }
    __syncthreads();

    // ---- Phase 1: conv. thread = (c = tid&31, tg = tid>>5), 8 t's each ----
    {
        const int c  = tid & 31;
        const int tg = tid >> 5;
        float acc[8];
#pragma unroll
        for (int j = 0; j < 8; ++j) acc[j] = 0.f;
#pragma unroll
        for (int ch = 0; ch < 2; ++ch) {
            float awr[KSIZE + 7];   // 38-float sliding window in registers
#pragma unroll
            for (int j = 0; j < KSIZE + 7; ++j) awr[j] = aw_lds[ch][tg * 8 + j];
#pragma unroll
            for (int k = 0; k < KSIZE; ++k) {
                float cv = cw_lds[c][ch][k];   // 2-way broadcast, free
#pragma unroll
                for (int j = 0; j < 8; ++j) acc[j] += cv * awr[k + j];
            }
        }
#pragma unroll
        for (int j = 0; j < 8; ++j) loc_lds[tg * 8 + j][c] = acc[j];
    }
    __syncthreads();

    // ---- Phase 2: 4 t's x 8 a's per thread, K split into 4 chunks of 8 ----
#pragma unroll
    for (int h = 0; h < 4; ++h) {
        float lrh[4][8];
#pragma unroll
        for (int jj = 0; jj < 4; ++jj) {
            *((float4*)&lrh[jj][0]) = *((const float4*)&loc_lds[tb + jj][8 * h]);
            *((float4*)&lrh[jj][4]) = *((const float4*)&loc_lds[tb + jj][8 * h + 4]);
        }
#pragma unroll
        for (int aa = 0; aa < 8; ++aa) {
            const int a = AL + 16 * aa;
            float4 w0 = *((const float4*)&wl_lds[a][8 * h]);
            float4 w1 = *((const float4*)&wl_lds[a][8 * h + 4]);
#pragma unroll
            for (int jj = 0; jj < 4; ++jj) {
                acc_e[jj][aa] +=
                      w0.x * lrh[jj][0] + w0.y * lrh[jj][1]
                    + w0.z * lrh[jj][2] + w0.w * lrh[jj][3]
                    + w1.x * lrh[jj][4] + w1.y * lrh[jj][5]
                    + w1.z * lrh[jj][6] + w1.w * lrh[jj][7];
            }
        }
    }

    // ---- epilogue: e = acc_e + pq; tanh; v-dot; reduce over 16 AL lanes ----
    float acc[4] = {0.f, 0.f, 0.f, 0.f};
#pragma unroll
    for (int aa = 0; aa < 8; ++aa) {
        const int a = AL + 16 * aa;
        const float pqa = pq_lds[a];
        const float va  = v_lds[a];
#pragma unroll
        for (int jj = 0; jj < 4; ++jj) {
            float e = acc_e[jj][aa] + pqa;
            // fast tanh: 1 - 2/(1+exp(2e)); ~5 VALU ops, abs err ~1e-6
            float ex = __expf(2.f * e);
            float th = 1.f - 2.f * __builtin_amdgcn_rcpf(1.f + ex);
            acc[jj] += va * th;
        }
    }
#pragma unroll
    for (int jj = 0; jj < 4; ++jj) {
        float s = acc[jj];
        s += __shfl_xor(s, 1, 64);
        s += __shfl_xor(s, 2, 64);
        s += __shfl_xor(s, 4, 64);
        s += __shfl_xor(s, 8, 64);
        if (AL == 0) {
            int t = t0 + tb + jj;
            if (t < T) energy[b * T + t] = s;
        }
    }
}

// ---------------------------------------------------------------------------
// Kernel 3 (R7): fused softmax + context. Grid (64 b, 16 e-slices of 32
// floats), 256 threads.
//  - Softmax computed redundantly per block (inputs identical -> outputs
//    identical): energy row is a 4 KB L2 read; softmax VALU/LDS work runs
//    WHILE the first 8 KB/wave of memory[] HBM loads are in flight (energy
//    loads issued first so their vmcnt drains without waiting on HBM).
//  - y==0 blocks write the normalized weights to the d_out tail.
//  - Context phase software-pipelined with explicit A/B register buffers:
//    issue tile k+1's 8 coalesced 128 B-segment loads before consuming tile
//    k (old version's unroll-1 loop serialized issue->stall->consume).
//  - No atomics: shfl butterfly + 128 B LDS reduce + one plain store.
// ---------------------------------------------------------------------------
__global__ __launch_bounds__(256) void softmax_context_kernel(
    const float* __restrict__ memory,        // (B, T, 512)
    const float* __restrict__ energy,        // (B, T) in ws
    const unsigned char* __restrict__ mask,  // (B, T) bool
    float* __restrict__ out)                 // [B*512 ctx][B*1000 weights]
{
    __shared__ float w_lds[1024];            // normalized weights, pad = 0
    __shared__ float sred[4];
    __shared__ float cred[4][ESL];

    const int b   = blockIdx.x;
    const int e0  = blockIdx.y * ESL;
    const int tid = threadIdx.x;
    const int col = tid & 7;            // float4 index within 32-float slice
    const int rg  = tid >> 3;           // 0..31 row-group

    // ---- (1) energy + mask loads FIRST (L2-resident, drain early) ----
    float e[4];
#pragma unroll
    for (int j = 0; j < 4; ++j) {
        int t = tid + j * 256;
        bool ok = (t < T);
        float val = ok ? energy[b * T + t] : -INFINITY;
        unsigned char m = ok ? mask[b * T + t] : (unsigned char)1;
        e[j] = (ok && !m) ? val : -INFINITY;
    }

    // ---- (2) prefetch context tile 0 (rows 0..255; no clamp needed) ----
    const float4* mem4 = (const float4*)(memory + (size_t)b * T * EMB_DIM + e0);
    float4 mA[8], mB[8];
#pragma unroll
    for (int u = 0; u < 8; ++u)
        mA[u] = mem4[(size_t)(rg + 32 * u) * 128 + col];

    // ---- (3) softmax while tile-0 HBM loads fly ----
    float mx = fmaxf(fmaxf(e[0], e[1]), fmaxf(e[2], e[3]));
#pragma unroll
    for (int off = 32; off > 0; off >>= 1)
        mx = fmaxf(mx, __shfl_down(mx, off, 64));
    if ((tid & 63) == 0) sred[tid >> 6] = mx;
    __syncthreads();
    mx = fmaxf(fmaxf(sred[0], sred[1]), fmaxf(sred[2], sred[3]));
    __syncthreads();

    float sum = 0.f;
    float ex[4];
#pragma unroll
    for (int j = 0; j < 4; ++j) {
        ex[j] = (e[j] == -INFINITY) ? 0.f : __expf(e[j] - mx);
        sum += ex[j];
    }
#pragma unroll
    for (int off = 32; off > 0; off >>= 1)
        sum += __shfl_down(sum, off, 64);
    if ((tid & 63) == 0) sred[tid >> 6] = sum;
    __syncthreads();
    sum = sred[0] + sred[1] + sred[2] + sred[3];
    float inv = 1.f / sum;

#pragma unroll
    for (int j = 0; j < 4; ++j) {
        int t = tid + j * 256;
        float wv = ex[j] * inv;
        w_lds[t] = (t < T) ? wv : 0.f;           // pads 1000..1023 = 0
        if (blockIdx.y == 0 && t < T)
            out[B * EMB_DIM + b * T + t] = wv;   // weights output
    }
    __syncthreads();   // w_lds ready

    // ---- (4) pipelined context accumulation ----
    float4 acc = {0.f, 0.f, 0.f, 0.f};

#define CTX_ISSUE(buf, base)                                              \
    _Pragma("unroll")                                                     \
    for (int u = 0; u < 8; ++u)                                           \
        buf[u] = mem4[(size_t)((base) + rg + 32 * u) * 128 + col];

#define CTX_ISSUE_CLAMP(buf, base)                                        \
    _Pragma("unroll")                                                     \
    for (int u = 0; u < 8; ++u) {                                         \
        int r  = (base) + rg + 32 * u;                                    \
        int rc = (r < T) ? r : (T - 1);                                   \
        buf[u] = mem4[(size_t)rc * 128 + col];                            \
    }

#define CTX_CONSUME(buf, base)                                            \
    _Pragma("unroll")                                                     \
    for (int u = 0; u < 8; ++u) {                                         \
        float wt = w_lds[(base) + rg + 32 * u];                           \
        acc.x += wt * buf[u].x; acc.y += wt * buf[u].y;                   \
        acc.z += wt * buf[u].z; acc.w += wt * buf[u].w;                   \
    }

    CTX_ISSUE(mB, 256)          // tile 1 in flight
    CTX_CONSUME(mA, 0)          // tile 0
    CTX_ISSUE(mA, 512)          // tile 2 in flight
    CTX_CONSUME(mB, 256)        // tile 1
    CTX_ISSUE_CLAMP(mB, 768)    // tile 3 in flight (rows up to 1023 clamped)
    CTX_CONSUME(mA, 512)        // tile 2
    CTX_CONSUME(mB, 768)        // tile 3 (pad rows killed by w=0)

#undef CTX_ISSUE
#undef CTX_ISSUE_CLAMP
#undef CTX_CONSUME

    // in-wave butterfly over the 8 rg-groups (lanes l^8, l^16, l^32; col fixed)
    acc.x += __shfl_xor(acc.x, 8, 64);  acc.x += __shfl_xor(acc.x, 16, 64);  acc.x += __shfl_xor(acc.x, 32, 64);
    acc.y += __shfl_xor(acc.y, 8, 64);  acc.y += __shfl_xor(acc.y, 16, 64);  acc.y += __shfl_xor(acc.y, 32, 64);
    acc.z += __shfl_xor(acc.z, 8, 64);  acc.z += __shfl_xor(acc.z, 16, 64);  acc.z += __shfl_xor(acc.z, 32, 64);
    acc.w += __shfl_xor(acc.w, 8, 64);  acc.w += __shfl_xor(acc.w, 16, 64);  acc.w += __shfl_xor(acc.w, 32, 64);

    if ((tid & 63) < 8)
        *((float4*)&cred[tid >> 6][4 * col]) = acc;
    __syncthreads();
    if (tid < ESL) {
        float s = cred[0][tid] + cred[1][tid] + cred[2][tid] + cred[3][tid];
        out[b * EMB_DIM + e0 + tid] = s;
    }
}

// ---------------------------------------------------------------------------
extern "C" void kernel_launch(void* const* d_in, const int* in_sizes, int n_in,
                              void* d_out, int out_size, void* d_ws, size_t ws_size,
                              hipStream_t stream) {
    const float* hidden = (const float*)d_in[0];            // (64, 1024)
    const float* memory = (const float*)d_in[1];            // (64, 1000, 512)
    const float* pm     = (const float*)d_in[2];            // (64, 1000, 128)
    const float* aw     = (const float*)d_in[3];            // (64, 2, 1000)
    const unsigned char* mask = (const unsigned char*)d_in[4]; // (64, 1000) bool
    const float* Wq     = (const float*)d_in[5];            // (128, 1024)
    const float* cw     = (const float*)d_in[6];            // (32, 2, 31)
    const float* wl     = (const float*)d_in[7];            // (128, 32)
    const float* v      = (const float*)d_in[8];            // (1, 128)

    float* out = (float*)d_out;            // [B*512 context][B*1000 weights]

    // workspace layout
    float* pq_ws     = (float*)d_ws;                   // B*128
    float* energy_ws = pq_ws + B * ATT_DIM;            // B*T

    // 1) query projection: 8192 waves
    pq_kernel<<<dim3((B * ATT_DIM) / 4), dim3(256), 0, stream>>>(hidden, Wq, pq_ws);

    // 2) fused conv/proj/tanh/v-dot -> energy  (16 tiles of 64 t)
    energy_kernel<<<dim3(B, (T + ET - 1) / ET), dim3(256), 0, stream>>>(
        aw, cw, wl, pq_ws, pm, v, energy_ws);

    // 3) fused softmax + context: (64 b, 16 e-slices)
    softmax_context_kernel<<<dim3(B, EMB_DIM / ESL), dim3(256), 0, stream>>>(
        memory, energy_ws, mask, out);
}

// Round 6
// 240.192 us; speedup vs baseline: 1.3583x; 1.1149x over previous
//
#include <hip/hip_runtime.h>
#include <hip/hip_bf16.h>
#include <math.h>

// Problem constants
#define B 64
#define T 1000
#define RNN_DIM 1024
#define EMB_DIM 512
#define ATT_DIM 128
#define LOC_DIM 32
#define KSIZE 31
#define PAD 15          // SAME padding for K=31
#define ET 64           // t-positions per energy block (16 tiles, last partial)
#define ESL 32          // e-floats per context block slice (16 slices)

typedef __attribute__((ext_vector_type(4))) float f32x4;
typedef __attribute__((ext_vector_type(8))) short bf16x8;

__device__ inline unsigned short bf16_rne(float x) {
    unsigned u = __float_as_uint(x);
    u += 0x7fff + ((u >> 16) & 1);          // round-to-nearest-even
    return (unsigned short)(u >> 16);
}

// ---------------------------------------------------------------------------
// Kernel 1: pq[b][a] = dot(hidden[b, :1024], Wq[a, :1024])
// One wave per output. 8192 outputs -> 2048 blocks x 256 threads. (~5 us, L2-fed)
// ---------------------------------------------------------------------------
__global__ __launch_bounds__(256) void pq_kernel(
    const float* __restrict__ hidden,   // (B, 1024)
    const float* __restrict__ Wq,       // (128, 1024)
    float* __restrict__ pq)             // (B, 128)
{
    int gwave = (blockIdx.x * blockDim.x + threadIdx.x) >> 6;
    int lane  = threadIdx.x & 63;
    int b = gwave >> 7;     // / 128
    int a = gwave & 127;

    const float4* h4 = (const float4*)(hidden + (size_t)b * RNN_DIM);
    const float4* w4 = (const float4*)(Wq + (size_t)a * RNN_DIM);

    float acc = 0.f;
#pragma unroll
    for (int j = 0; j < 4; ++j) {
        float4 h = h4[j * 64 + lane];
        float4 w = w4[j * 64 + lane];
        acc += h.x * w.x + h.y * w.y + h.z * w.z + h.w * w.w;
    }
#pragma unroll
    for (int off = 32; off > 0; off >>= 1)
        acc += __shfl_down(acc, off, 64);
    if (lane == 0) pq[gwave] = acc;
}

// ---------------------------------------------------------------------------
// Kernel 2 (R9): fused location conv + W_loc projection (MFMA) + tanh + v-dot.
// R5's MFMA port timed well (242 total) but failed the replay-determinism
// tripwire: first launch good, all later launches stably bad => scratch
// state. Suspect: __launch_bounds__(256,4) VGPR cap + 32 acc regs held live
// across staging+conv forced accumulator spill/reload around the MFMA block.
// R9 removes the spill conditions:
//  - no min-waves pin (plain 256); LDS 33.5 KB still allows 4 blocks/CU.
//  - pm preload moved AFTER conv (conv regs dead) -> peak pressure ~80 VGPR,
//    no phase overlap, no spill at default allocation.
//  - predicated (t<T ? load : 0) instead of clamped-address reads.
// MFMA structure unchanged from R5 (initial check passed => layouts right):
// E(64x128) = loc(64x32) x wl^T, 2-term split bf16 (hi*hi + hi*lo + lo*hi,
// dropped lo*lo ~2^-18 rel). Per wave: 24 MFMA + ~20 b128 LDS reads vs
// ~1024 scalar FMA + 96 b128 in the R2 fp32 version.
// Fragment layouts: A row=lane&15, B col=lane&15, k=8*(lane>>4)+j (A/B use
// the same k-map so any k-permutation cancels in the dot product);
// C/D col=lane&15, row=(lane>>4)*4+reg [m89-verified].
// ---------------------------------------------------------------------------
__global__ __launch_bounds__(256) void energy_kernel(
    const float* __restrict__ aw,       // (B, 2, T)
    const float* __restrict__ cw,       // (32, 2, 31)
    const float* __restrict__ wl,       // (128, 32)
    const float* __restrict__ pq,       // (B, 128)
    const float* __restrict__ pm,       // (B, T, 128)
    const float* __restrict__ v,        // (128)
    float* __restrict__ energy)         // (B, T)
{
    __shared__ float aw_lds[2][ET + 2 * PAD];     // [2][94]
    __shared__ float cw_lds[LOC_DIM][2][KSIZE];   // 2-way, free
    __shared__ __align__(16) unsigned short wl_hi[ATT_DIM][LOC_DIM];  // bf16
    __shared__ __align__(16) unsigned short wl_lo[ATT_DIM][LOC_DIM];  // bf16
    __shared__ __align__(16) unsigned short loc_hi[ET][LOC_DIM];      // bf16
    __shared__ __align__(16) unsigned short loc_lo[ET][LOC_DIM];      // bf16
    __shared__ float pq_lds[ATT_DIM];
    __shared__ float v_lds[ATT_DIM];

    const int b   = blockIdx.x;
    const int t0  = blockIdx.y * ET;
    const int tid = threadIdx.x;

    const int w   = tid >> 6;     // wave 0..3: owns t rows [16w, 16w+16)
    const int l   = tid & 63;
    const int c15 = l & 15;       // A-row / B-col / C-col within tile
    const int g   = l >> 4;       // k-group (frags), C row-group

    // ---- stage small weights ----
    for (int i = tid; i < LOC_DIM * 2 * KSIZE; i += 256)
        ((float*)cw_lds)[i] = cw[i];
    // wl -> pre-split bf16 hi/lo (once per block; removes all hot-loop cvt)
    for (int i = tid; i < ATT_DIM * LOC_DIM; i += 256) {
        float x = wl[i];
        unsigned short h = bf16_rne(x);
        float hf = __uint_as_float((unsigned)h << 16);
        wl_hi[i >> 5][i & 31] = h;
        wl_lo[i >> 5][i & 31] = bf16_rne(x - hf);
    }
    if (tid < ATT_DIM) {
        pq_lds[tid] = pq[b * ATT_DIM + tid];
        v_lds[tid]  = v[tid];
    }
    for (int i = tid; i < 2 * (ET + 2 * PAD); i += 256) {
        int ch = i / (ET + 2 * PAD);
        int p  = i % (ET + 2 * PAD);
        int t  = t0 + p - PAD;
        aw_lds[ch][p] = (t >= 0 && t < T) ? aw[(size_t)b * 2 * T + ch * T + t] : 0.f;
    }
    __syncthreads();

    // ---- Phase 1: conv. thread = (c = tid&31, tg = tid>>5), 8 t's each.
    //      Output written directly as split bf16 (b16 stores, 2-way banks).
    {
        const int c  = tid & 31;
        const int tg = tid >> 5;
        float cacc[8];
#pragma unroll
        for (int j = 0; j < 8; ++j) cacc[j] = 0.f;
#pragma unroll
        for (int ch = 0; ch < 2; ++ch) {
            float awr[KSIZE + 7];   // 38-float sliding window in registers
#pragma unroll
            for (int j = 0; j < KSIZE + 7; ++j) awr[j] = aw_lds[ch][tg * 8 + j];
#pragma unroll
            for (int k = 0; k < KSIZE; ++k) {
                float cv = cw_lds[c][ch][k];   // 2-way broadcast, free
#pragma unroll
                for (int j = 0; j < 8; ++j) cacc[j] += cv * awr[k + j];
            }
        }
#pragma unroll
        for (int j = 0; j < 8; ++j) {
            float x = cacc[j];
            unsigned short h = bf16_rne(x);
            float hf = __uint_as_float((unsigned)h << 16);
            loc_hi[tg * 8 + j][c] = h;
            loc_lo[tg * 8 + j][c] = bf16_rne(x - hf);
        }
    }

    // ---- pm -> MFMA C-in accumulator, AFTER conv (conv regs dead here).
    //      acc[n][r] = pm[t0+16w+4g+r][16n+c15]; per (n,r): 4 t-rows x 64 B
    //      contiguous segments. Loads drain under the barrier + MFMA issue.
    f32x4 acc[8];
    {
        const float* pmb = pm + (size_t)b * T * ATT_DIM;
        const int tbase = t0 + 16 * w + 4 * g;
#pragma unroll
        for (int n = 0; n < 8; ++n) {
#pragma unroll
            for (int r = 0; r < 4; ++r) {
                int t = tbase + r;
                acc[n][r] = (t < T) ? pmb[(size_t)t * ATT_DIM + 16 * n + c15] : 0.f;
            }
        }
    }
    __syncthreads();

    // ---- Phase 2: E(64x128) = loc(64x32) x wl^T via MFMA, split-bf16.
    //      A frag: loc[16w + c15][8g..8g+7]; B frag: wl[16n + c15][8g..8g+7].
    //      acc already holds pm. 3 MFMA per a-tile: aH*bH + aH*bL + aL*bH.
    {
        bf16x8 aH = *(const bf16x8*)&loc_hi[16 * w + c15][8 * g];
        bf16x8 aL = *(const bf16x8*)&loc_lo[16 * w + c15][8 * g];
#pragma unroll
        for (int n = 0; n < 8; ++n) {
            bf16x8 bH = *(const bf16x8*)&wl_hi[16 * n + c15][8 * g];
            bf16x8 bL = *(const bf16x8*)&wl_lo[16 * n + c15][8 * g];
            acc[n] = __builtin_amdgcn_mfma_f32_16x16x32_bf16(aH, bH, acc[n], 0, 0, 0);
            acc[n] = __builtin_amdgcn_mfma_f32_16x16x32_bf16(aH, bL, acc[n], 0, 0, 0);
            acc[n] = __builtin_amdgcn_mfma_f32_16x16x32_bf16(aL, bH, acc[n], 0, 0, 0);
        }
    }

    // ---- epilogue: e = acc + pq; tanh; v-dot; reduce over the 16-lane
    //      column group (C col = c15), t = t0 + 16w + 4g + r per (g, r).
    {
        float s[4] = {0.f, 0.f, 0.f, 0.f};
#pragma unroll
        for (int n = 0; n < 8; ++n) {
            const float pqa = pq_lds[16 * n + c15];
            const float va  = v_lds[16 * n + c15];
#pragma unroll
            for (int r = 0; r < 4; ++r) {
                float e = acc[n][r] + pqa;
                // fast tanh: 1 - 2/(1+exp(2e)); ~5 VALU ops, abs err ~1e-6
                float ex = __expf(2.f * e);
                float th = 1.f - 2.f * __builtin_amdgcn_rcpf(1.f + ex);
                s[r] += va * th;
            }
        }
#pragma unroll
        for (int r = 0; r < 4; ++r) {
            s[r] += __shfl_xor(s[r], 1, 64);
            s[r] += __shfl_xor(s[r], 2, 64);
            s[r] += __shfl_xor(s[r], 4, 64);
            s[r] += __shfl_xor(s[r], 8, 64);
        }
        if (c15 == 0) {
            const int tbase = t0 + 16 * w + 4 * g;
#pragma unroll
            for (int r = 0; r < 4; ++r) {
                int t = tbase + r;
                if (t < T) energy[b * T + t] = s[r];
            }
        }
    }
}

// ---------------------------------------------------------------------------
// Kernel 3: fused softmax + context (unchanged from R4, which passed all
// tripwires; near its 131 MB / 6.3 TB/s roofline).
// ---------------------------------------------------------------------------
__global__ __launch_bounds__(256) void softmax_context_kernel(
    const float* __restrict__ memory,        // (B, T, 512)
    const float* __restrict__ energy,        // (B, T) in ws
    const unsigned char* __restrict__ mask,  // (B, T) bool
    float* __restrict__ out)                 // [B*512 ctx][B*1000 weights]
{
    __shared__ float w_lds[1024];            // normalized weights, pad = 0
    __shared__ float sred[4];
    __shared__ float cred[4][ESL];

    const int b   = blockIdx.x;
    const int e0  = blockIdx.y * ESL;
    const int tid = threadIdx.x;
    const int col = tid & 7;            // float4 index within 32-float slice
    const int rg  = tid >> 3;           // 0..31 row-group

    // ---- (1) energy + mask loads FIRST (L2-resident, drain early) ----
    float e[4];
#pragma unroll
    for (int j = 0; j < 4; ++j) {
        int t = tid + j * 256;
        bool ok = (t < T);
        float val = ok ? energy[b * T + t] : -INFINITY;
        unsigned char m = ok ? mask[b * T + t] : (unsigned char)1;
        e[j] = (ok && !m) ? val : -INFINITY;
    }

    // ---- (2) prefetch context tile 0 (rows 0..255; no clamp needed) ----
    const float4* mem4 = (const float4*)(memory + (size_t)b * T * EMB_DIM + e0);
    float4 mA[8], mB[8];
#pragma unroll
    for (int u = 0; u < 8; ++u)
        mA[u] = mem4[(size_t)(rg + 32 * u) * 128 + col];

    // ---- (3) softmax while tile-0 HBM loads fly ----
    float mx = fmaxf(fmaxf(e[0], e[1]), fmaxf(e[2], e[3]));
#pragma unroll
    for (int off = 32; off > 0; off >>= 1)
        mx = fmaxf(mx, __shfl_down(mx, off, 64));
    if ((tid & 63) == 0) sred[tid >> 6] = mx;
    __syncthreads();
    mx = fmaxf(fmaxf(sred[0], sred[1]), fmaxf(sred[2], sred[3]));
    __syncthreads();

    float sum = 0.f;
    float ex[4];
#pragma unroll
    for (int j = 0; j < 4; ++j) {
        ex[j] = (e[j] == -INFINITY) ? 0.f : __expf(e[j] - mx);
        sum += ex[j];
    }
#pragma unroll
    for (int off = 32; off > 0; off >>= 1)
        sum += __shfl_down(sum, off, 64);
    if ((tid & 63) == 0) sred[tid >> 6] = sum;
    __syncthreads();
    sum = sred[0] + sred[1] + sred[2] + sred[3];
    float inv = 1.f / sum;

#pragma unroll
    for (int j = 0; j < 4; ++j) {
        int t = tid + j * 256;
        float wv = ex[j] * inv;
        w_lds[t] = (t < T) ? wv : 0.f;           // pads 1000..1023 = 0
        if (blockIdx.y == 0 && t < T)
            out[B * EMB_DIM + b * T + t] = wv;   // weights output
    }
    __syncthreads();   // w_lds ready

    // ---- (4) pipelined context accumulation ----
    float4 acc = {0.f, 0.f, 0.f, 0.f};

#define CTX_ISSUE(buf, base)                                              \
    _Pragma("unroll")                                                     \
    for (int u = 0; u < 8; ++u)                                           \
        buf[u] = mem4[(size_t)((base) + rg + 32 * u) * 128 + col];

#define CTX_ISSUE_CLAMP(buf, base)                                        \
    _Pragma("unroll")                                                     \
    for (int u = 0; u < 8; ++u) {                                         \
        int r  = (base) + rg + 32 * u;                                    \
        int rc = (r < T) ? r : (T - 1);                                   \
        buf[u] = mem4[(size_t)rc * 128 + col];                            \
    }

#define CTX_CONSUME(buf, base)                                            \
    _Pragma("unroll")                                                     \
    for (int u = 0; u < 8; ++u) {                                         \
        float wt = w_lds[(base) + rg + 32 * u];                           \
        acc.x += wt * buf[u].x; acc.y += wt * buf[u].y;                   \
        acc.z += wt * buf[u].z; acc.w += wt * buf[u].w;                   \
    }

    CTX_ISSUE(mB, 256)          // tile 1 in flight
    CTX_CONSUME(mA, 0)          // tile 0
    CTX_ISSUE(mA, 512)          // tile 2 in flight
    CTX_CONSUME(mB, 256)        // tile 1
    CTX_ISSUE_CLAMP(mB, 768)    // tile 3 in flight (rows up to 1023 clamped)
    CTX_CONSUME(mA, 512)        // tile 2
    CTX_CONSUME(mB, 768)        // tile 3 (pad rows killed by w=0)

#undef CTX_ISSUE
#undef CTX_ISSUE_CLAMP
#undef CTX_CONSUME

    // in-wave butterfly over the 8 rg-groups (lanes l^8, l^16, l^32; col fixed)
    acc.x += __shfl_xor(acc.x, 8, 64);  acc.x += __shfl_xor(acc.x, 16, 64);  acc.x += __shfl_xor(acc.x, 32, 64);
    acc.y += __shfl_xor(acc.y, 8, 64);  acc.y += __shfl_xor(acc.y, 16, 64);  acc.y += __shfl_xor(acc.y, 32, 64);
    acc.z += __shfl_xor(acc.z, 8, 64);  acc.z += __shfl_xor(acc.z, 16, 64);  acc.z += __shfl_xor(acc.z, 32, 64);
    acc.w += __shfl_xor(acc.w, 8, 64);  acc.w += __shfl_xor(acc.w, 16, 64);  acc.w += __shfl_xor(acc.w, 32, 64);

    if ((tid & 63) < 8)
        *((float4*)&cred[tid >> 6][4 * col]) = acc;
    __syncthreads();
    if (tid < ESL) {
        float s = cred[0][tid] + cred[1][tid] + cred[2][tid] + cred[3][tid];
        out[b * EMB_DIM + e0 + tid] = s;
    }
}

// ---------------------------------------------------------------------------
extern "C" void kernel_launch(void* const* d_in, const int* in_sizes, int n_in,
                              void* d_out, int out_size, void* d_ws, size_t ws_size,
                              hipStream_t stream) {
    const float* hidden = (const float*)d_in[0];            // (64, 1024)
    const float* memory = (const float*)d_in[1];            // (64, 1000, 512)
    const float* pm     = (const float*)d_in[2];            // (64, 1000, 128)
    const float* aw     = (const float*)d_in[3];            // (64, 2, 1000)
    const unsigned char* mask = (const unsigned char*)d_in[4]; // (64, 1000) bool
    const float* Wq     = (const float*)d_in[5];            // (128, 1024)
    const float* cw     = (const float*)d_in[6];            // (32, 2, 31)
    const float* wl     = (const float*)d_in[7];            // (128, 32)
    const float* v      = (const float*)d_in[8];            // (1, 128)

    float* out = (float*)d_out;            // [B*512 context][B*1000 weights]

    // workspace layout
    float* pq_ws     = (float*)d_ws;                   // B*128
    float* energy_ws = pq_ws + B * ATT_DIM;            // B*T

    // 1) query projection: 8192 waves
    pq_kernel<<<dim3((B * ATT_DIM) / 4), dim3(256), 0, stream>>>(hidden, Wq, pq_ws);

    // 2) fused conv/proj(MFMA)/tanh/v-dot -> energy  (16 tiles of 64 t)
    energy_kernel<<<dim3(B, (T + ET - 1) / ET), dim3(256), 0, stream>>>(
        aw, cw, wl, pq_ws, pm, v, energy_ws);

    // 3) fused softmax + context: (64 b, 16 e-slices)
    softmax_context_kernel<<<dim3(B, EMB_DIM / ESL), dim3(256), 0, stream>>>(
        memory, energy_ws, mask, out);
}